// Round 8
// baseline (75.819 us; speedup 1.0000x reference)
//
#include <hip/hip_runtime.h>

#define TPB 256

typedef __attribute__((ext_vector_type(8))) short bf16x8;
typedef __attribute__((ext_vector_type(4))) float f32x4;

__device__ __forceinline__ unsigned pack_bf16_rne(float lo, float hi) {
    union { float f; unsigned u; } a, b;
    a.f = lo; b.f = hi;
    unsigned ua = (a.u + 0x7fffu + ((a.u >> 16) & 1u)) >> 16;
    unsigned ub = (b.u + 0x7fffu + ((b.u >> 16) & 1u)) >> 16;
    return ua | (ub << 16);
}
__device__ __forceinline__ float bf_lo(unsigned u) {
    union { unsigned i; float f; } c; c.i = u << 16; return c.f;
}
__device__ __forceinline__ float bf_hi(unsigned u) {
    union { unsigned i; float f; } c; c.i = u & 0xffff0000u; return c.f;
}

// ---- prep: valproj bf16 [K,64] = bf16(values) @ bf16(W), via MFMA ----
// Block = 64 table rows, 4 waves x 16 rows. Verified fragment mapping from
// rounds 4-7: A row = l&15, k = kf*32 + 8*(l>>4) + j; B col = ct*16 + (l&15),
// same k; C col = l&15, row = 4*(l>>4) + r.
__global__ __launch_bounds__(TPB) void proj_table_mfma(
    const float* __restrict__ values,   // [K,64] fp32
    const float* __restrict__ W,        // [64,64] fp32
    unsigned short* __restrict__ vp,    // [K,64] bf16 out
    int K)
{
    const int t    = threadIdx.x;
    const int l    = t & 63;
    const int w    = t >> 6;
    const int r0   = blockIdx.x * 64 + 16 * w;   // wave's 16-row tile
    const int srow = l & 15;
    const int kq   = l >> 4;

    int row = r0 + srow;
    if (row >= K) row = K - 1;                   // clamped rows never stored

    // A-fragments from fp32 values
    bf16x8 af[2];
    #pragma unroll
    for (int kf = 0; kf < 2; ++kf) {
        const float4 x0 = *(const float4*)&values[(size_t)row * 64 + kf * 32 + 8 * kq];
        const float4 x1 = *(const float4*)&values[(size_t)row * 64 + kf * 32 + 8 * kq + 4];
        union { unsigned u[4]; bf16x8 v; } cv;
        cv.u[0] = pack_bf16_rne(x0.x, x0.y);
        cv.u[1] = pack_bf16_rne(x0.z, x0.w);
        cv.u[2] = pack_bf16_rne(x1.x, x1.y);
        cv.u[3] = pack_bf16_rne(x1.z, x1.w);
        af[kf] = cv.v;
    }

    #pragma unroll
    for (int ct = 0; ct < 4; ++ct) {
        const int col = ct * 16 + srow;
        f32x4 acc;
        acc[0] = 0.f; acc[1] = 0.f; acc[2] = 0.f; acc[3] = 0.f;
        #pragma unroll
        for (int kf = 0; kf < 2; ++kf) {
            const int k0 = kf * 32 + 8 * kq;
            union { unsigned u[4]; bf16x8 v; } bv;   // B-frag inline from fp32 W (L1-hot)
            bv.u[0] = pack_bf16_rne(W[(k0 + 0) * 64 + col], W[(k0 + 1) * 64 + col]);
            bv.u[1] = pack_bf16_rne(W[(k0 + 2) * 64 + col], W[(k0 + 3) * 64 + col]);
            bv.u[2] = pack_bf16_rne(W[(k0 + 4) * 64 + col], W[(k0 + 5) * 64 + col]);
            bv.u[3] = pack_bf16_rne(W[(k0 + 6) * 64 + col], W[(k0 + 7) * 64 + col]);
            acc = __builtin_amdgcn_mfma_f32_16x16x32_bf16(af[kf], bv.v, acc, 0, 0, 0);
        }
        #pragma unroll
        for (int r = 0; r < 4; ++r) {
            const int orow = r0 + 4 * kq + r;
            if (orow < K) {
                union { float f; unsigned u; } a; a.f = acc[r];
                const unsigned us = (a.u + 0x7fffu + ((a.u >> 16) & 1u)) >> 16;
                vp[(size_t)orow * 64 + col] = (unsigned short)us;
            }
        }
    }
}

// ---- hot kernel: gather + trilinear weighted sum + bias, NO matmul ----
// Wave w owns 16 samples. Lane l: sample srow = l&15, dim octets 8*kq.. and
// 32+8*kq.. (kq = l>>4). 4 lanes per sample cover the full 128B valproj row
// exactly once -> coalesced line-merged gathers. All 16 gathers issued in one
// batch (one vmcnt window). Output: 4 float4 NT stores per lane.
__global__ __launch_bounds__(TPB) void gather_interp(
    const unsigned* __restrict__ vp,     // [K,32] u32 = 64 bf16 (128 B/row)
    const float* __restrict__ p,         // [N,3]
    const float* __restrict__ b,         // [64]
    const int*   __restrict__ feats,     // [V,8]
    const int*   __restrict__ vidx,      // [N]
    float* __restrict__ out,             // [N,64]
    int N)
{
    const int t    = threadIdx.x;
    const int l    = t & 63;
    const int w    = t >> 6;
    const int base = blockIdx.x * 64 + 16 * w;
    const int srow = l & 15;
    const int kq   = l >> 4;

    const bool valid = (base + srow) < N;
    int n = base + srow;
    if (!valid) n = N - 1;

    // ---- corner indices + trilinear weights ----
    const int v = vidx[n];
    const int4 f0 = *(const int4*)&feats[(size_t)v * 8];
    const int4 f1 = *(const int4*)&feats[(size_t)v * 8 + 4];

    const float px = p[n * 3 + 0];
    const float py = p[n * 3 + 1];
    const float pz = p[n * 3 + 2];
    const float ox = 1.0f - px, oy = 1.0f - py, oz = 1.0f - pz;
    // corner order: [1,1,1],[1,1,0],[1,0,1],[0,1,1],[1,0,0],[0,1,0],[0,0,1],[0,0,0]
    float wgt[8];
    wgt[0] = px * py * pz;
    wgt[1] = px * py * oz;
    wgt[2] = px * oy * pz;
    wgt[3] = ox * py * pz;
    wgt[4] = px * oy * oz;
    wgt[5] = ox * py * oz;
    wgt[6] = ox * oy * pz;
    wgt[7] = ox * oy * oz;
    const int cidx[8] = {f0.x, f0.y, f0.z, f0.w, f1.x, f1.y, f1.z, f1.w};

    // ---- issue ALL 16 gathers (one vmcnt window, max MLP) ----
    uint4 q0s[8], q1s[8];
    #pragma unroll
    for (int c = 0; c < 8; ++c) {
        const unsigned* row = vp + (size_t)cidx[c] * 32;
        q0s[c] = *(const uint4*)(row + 4 * kq);        // dims 8kq .. 8kq+7
        q1s[c] = *(const uint4*)(row + 16 + 4 * kq);   // dims 32+8kq .. +7
    }

    // ---- weighted accumulate (fp32) ----
    float a0[8] = {0.f,0.f,0.f,0.f,0.f,0.f,0.f,0.f};
    float a1[8] = {0.f,0.f,0.f,0.f,0.f,0.f,0.f,0.f};
    #pragma unroll
    for (int c = 0; c < 8; ++c) {
        const uint4 q0 = q0s[c];
        const uint4 q1 = q1s[c];
        const float wc = wgt[c];
        a0[0] = fmaf(wc, bf_lo(q0.x), a0[0]);
        a0[1] = fmaf(wc, bf_hi(q0.x), a0[1]);
        a0[2] = fmaf(wc, bf_lo(q0.y), a0[2]);
        a0[3] = fmaf(wc, bf_hi(q0.y), a0[3]);
        a0[4] = fmaf(wc, bf_lo(q0.z), a0[4]);
        a0[5] = fmaf(wc, bf_hi(q0.z), a0[5]);
        a0[6] = fmaf(wc, bf_lo(q0.w), a0[6]);
        a0[7] = fmaf(wc, bf_hi(q0.w), a0[7]);
        a1[0] = fmaf(wc, bf_lo(q1.x), a1[0]);
        a1[1] = fmaf(wc, bf_hi(q1.x), a1[1]);
        a1[2] = fmaf(wc, bf_lo(q1.y), a1[2]);
        a1[3] = fmaf(wc, bf_hi(q1.y), a1[3]);
        a1[4] = fmaf(wc, bf_lo(q1.z), a1[4]);
        a1[5] = fmaf(wc, bf_hi(q1.z), a1[5]);
        a1[6] = fmaf(wc, bf_lo(q1.w), a1[6]);
        a1[7] = fmaf(wc, bf_hi(q1.w), a1[7]);
    }

    // ---- bias + store (4 x float4 NT) ----
    if (valid) {
        const float4 b00 = *(const float4*)&b[8 * kq];
        const float4 b01 = *(const float4*)&b[8 * kq + 4];
        const float4 b10 = *(const float4*)&b[32 + 8 * kq];
        const float4 b11 = *(const float4*)&b[32 + 8 * kq + 4];
        float* o = out + (size_t)n * 64;
        __builtin_nontemporal_store(a0[0] + b00.x, o + 8 * kq + 0);
        __builtin_nontemporal_store(a0[1] + b00.y, o + 8 * kq + 1);
        __builtin_nontemporal_store(a0[2] + b00.z, o + 8 * kq + 2);
        __builtin_nontemporal_store(a0[3] + b00.w, o + 8 * kq + 3);
        __builtin_nontemporal_store(a0[4] + b01.x, o + 8 * kq + 4);
        __builtin_nontemporal_store(a0[5] + b01.y, o + 8 * kq + 5);
        __builtin_nontemporal_store(a0[6] + b01.z, o + 8 * kq + 6);
        __builtin_nontemporal_store(a0[7] + b01.w, o + 8 * kq + 7);
        __builtin_nontemporal_store(a1[0] + b10.x, o + 32 + 8 * kq + 0);
        __builtin_nontemporal_store(a1[1] + b10.y, o + 32 + 8 * kq + 1);
        __builtin_nontemporal_store(a1[2] + b10.z, o + 32 + 8 * kq + 2);
        __builtin_nontemporal_store(a1[3] + b10.w, o + 32 + 8 * kq + 3);
        __builtin_nontemporal_store(a1[4] + b11.x, o + 32 + 8 * kq + 4);
        __builtin_nontemporal_store(a1[5] + b11.y, o + 32 + 8 * kq + 5);
        __builtin_nontemporal_store(a1[6] + b11.z, o + 32 + 8 * kq + 6);
        __builtin_nontemporal_store(a1[7] + b11.w, o + 32 + 8 * kq + 7);
    }
}

// ---- fallback: proven round-2 fp32 kernel (used only if ws too small) ----
__global__ __launch_bounds__(TPB) void fused_embed_proj_fp32(
    const float* __restrict__ values, const float* __restrict__ p,
    const float* __restrict__ W, const float* __restrict__ b,
    const int* __restrict__ feats, const int* __restrict__ vidx,
    float* __restrict__ out, int N)
{
    __shared__ float featS[64][68];
    __shared__ float Wlds[64][64];

    const int t    = threadIdx.x;
    const int base = blockIdx.x * 64;
    {
        const float4* Wv = (const float4*)W;
        float4*       Wl = (float4*)&Wlds[0][0];
        #pragma unroll
        for (int i = 0; i < 4; ++i) Wl[t + i * TPB] = Wv[t + i * TPB];
    }
    const int g  = t & 15;
    const int sb = t >> 4;

    int   cidx[4][8];
    float wgt[4][8];
    #pragma unroll
    for (int i = 0; i < 4; ++i) {
        const int s = sb + 16 * i;
        int n = base + s;
        if (n >= N) n = N - 1;
        const int v = vidx[n];
        const int4 f0 = *(const int4*)&feats[(size_t)v * 8];
        const int4 f1 = *(const int4*)&feats[(size_t)v * 8 + 4];
        cidx[i][0] = f0.x; cidx[i][1] = f0.y; cidx[i][2] = f0.z; cidx[i][3] = f0.w;
        cidx[i][4] = f1.x; cidx[i][5] = f1.y; cidx[i][6] = f1.z; cidx[i][7] = f1.w;
        const float px = p[n * 3], py = p[n * 3 + 1], pz = p[n * 3 + 2];
        const float ox = 1.f - px, oy = 1.f - py, oz = 1.f - pz;
        wgt[i][0] = px * py * pz; wgt[i][1] = px * py * oz;
        wgt[i][2] = px * oy * pz; wgt[i][3] = ox * py * pz;
        wgt[i][4] = px * oy * oz; wgt[i][5] = ox * py * oz;
        wgt[i][6] = ox * oy * pz; wgt[i][7] = ox * oy * oz;
    }
    #pragma unroll
    for (int i = 0; i < 4; ++i) {
        float4 acc; acc.x = acc.y = acc.z = acc.w = 0.f;
        #pragma unroll
        for (int c = 0; c < 8; ++c) {
            const float4 val = *(const float4*)&values[(size_t)cidx[i][c] * 64 + 4 * g];
            const float w = wgt[i][c];
            acc.x = fmaf(w, val.x, acc.x); acc.y = fmaf(w, val.y, acc.y);
            acc.z = fmaf(w, val.z, acc.z); acc.w = fmaf(w, val.w, acc.w);
        }
        *(float4*)&featS[sb + 16 * i][4 * g] = acc;
    }
    __syncthreads();

    const int tx = t & 15, ty = t >> 4;
    float acc[4][4];
    {
        const float4 bb = ((const float4*)b)[tx];
        #pragma unroll
        for (int j = 0; j < 4; ++j) {
            acc[j][0] = bb.x; acc[j][1] = bb.y; acc[j][2] = bb.z; acc[j][3] = bb.w;
        }
    }
    #pragma unroll 4
    for (int d = 0; d < 64; ++d) {
        const float a0 = featS[4 * ty + 0][d];
        const float a1 = featS[4 * ty + 1][d];
        const float a2 = featS[4 * ty + 2][d];
        const float a3 = featS[4 * ty + 3][d];
        const float4 wr = *(const float4*)&Wlds[d][4 * tx];
        acc[0][0] = fmaf(a0, wr.x, acc[0][0]); acc[0][1] = fmaf(a0, wr.y, acc[0][1]);
        acc[0][2] = fmaf(a0, wr.z, acc[0][2]); acc[0][3] = fmaf(a0, wr.w, acc[0][3]);
        acc[1][0] = fmaf(a1, wr.x, acc[1][0]); acc[1][1] = fmaf(a1, wr.y, acc[1][1]);
        acc[1][2] = fmaf(a1, wr.z, acc[1][2]); acc[1][3] = fmaf(a1, wr.w, acc[1][3]);
        acc[2][0] = fmaf(a2, wr.x, acc[2][0]); acc[2][1] = fmaf(a2, wr.y, acc[2][1]);
        acc[2][2] = fmaf(a2, wr.z, acc[2][2]); acc[2][3] = fmaf(a2, wr.w, acc[2][3]);
        acc[3][0] = fmaf(a3, wr.x, acc[3][0]); acc[3][1] = fmaf(a3, wr.y, acc[3][1]);
        acc[3][2] = fmaf(a3, wr.z, acc[3][2]); acc[3][3] = fmaf(a3, wr.w, acc[3][3]);
    }
    #pragma unroll
    for (int j = 0; j < 4; ++j) {
        const int n = base + 4 * ty + j;
        if (n < N) {
            float4 o; o.x = acc[j][0]; o.y = acc[j][1]; o.z = acc[j][2]; o.w = acc[j][3];
            *(float4*)&out[(size_t)n * 64 + 4 * tx] = o;
        }
    }
}

extern "C" void kernel_launch(void* const* d_in, const int* in_sizes, int n_in,
                              void* d_out, int out_size, void* d_ws, size_t ws_size,
                              hipStream_t stream) {
    const float* values = (const float*)d_in[0];
    const float* p      = (const float*)d_in[1];
    const float* W      = (const float*)d_in[2];
    const float* b      = (const float*)d_in[3];
    const int*   feats  = (const int*)d_in[4];
    const int*   vidx   = (const int*)d_in[5];
    float* out = (float*)d_out;

    const int N  = in_sizes[5];
    const int KD = in_sizes[0];            // K * 64
    const int K  = KD / 64;
    const int nblocks = (N + 63) / 64;

    const size_t need = (size_t)KD * 2;    // valproj bf16 bytes
    if (ws_size >= need) {
        unsigned short* vp = (unsigned short*)d_ws;
        const int kblocks = (K + 63) / 64;
        proj_table_mfma<<<kblocks, TPB, 0, stream>>>(values, W, vp, K);
        gather_interp<<<nblocks, TPB, 0, stream>>>(
            (const unsigned*)vp, p, b, feats, vidx, out, N);
    } else {
        fused_embed_proj_fp32<<<nblocks, TPB, 0, stream>>>(
            values, p, W, b, feats, vidx, out, N);
    }
}

// Round 9
// 72.211 us; speedup vs baseline: 1.0500x; 1.0500x over previous
//
#include <hip/hip_runtime.h>

#define TPB 256

typedef __attribute__((ext_vector_type(8))) short bf16x8;
typedef __attribute__((ext_vector_type(4))) float f32x4;

__device__ __forceinline__ unsigned pack_bf16_rne(float lo, float hi) {
    union { float f; unsigned u; } a, b;
    a.f = lo; b.f = hi;
    unsigned ua = (a.u + 0x7fffu + ((a.u >> 16) & 1u)) >> 16;
    unsigned ub = (b.u + 0x7fffu + ((b.u >> 16) & 1u)) >> 16;
    return ua | (ub << 16);
}
__device__ __forceinline__ unsigned short bf16_rne1(float x) {
    union { float f; unsigned u; } a; a.f = x;
    return (unsigned short)((a.u + 0x7fffu + ((a.u >> 16) & 1u)) >> 16);
}
__device__ __forceinline__ float bf_lo(unsigned u) {
    union { unsigned i; float f; } c; c.i = u << 16; return c.f;
}
__device__ __forceinline__ float bf_hi(unsigned u) {
    union { unsigned i; float f; } c; c.i = u & 0xffff0000u; return c.f;
}

// ---- prep: valproj bf16 [K,64] = bf16(values) @ bf16(W), via MFMA ----
// Block = 64 table rows (4 waves x 16-row tiles). MFMA C-frags go through an
// 8KB LDS tile so the global write is fully-coalesced uint4 rows.
// Fragment mapping (verified rounds 4-8): A row = l&15, k = kf*32+8*(l>>4)+j;
// B col = ct*16+(l&15); C col = l&15, row = 4*(l>>4)+r.
__global__ __launch_bounds__(TPB) void proj_table_mfma(
    const float* __restrict__ values,   // [K,64] fp32
    const float* __restrict__ W,        // [64,64] fp32
    unsigned* __restrict__ vp,          // [K,32] u32 (=64 bf16) out
    int K)
{
    __shared__ unsigned short tile[64 * 64];   // [row_in_block][col]

    const int t    = threadIdx.x;
    const int l    = t & 63;
    const int w    = t >> 6;
    const int rb   = blockIdx.x * 64;            // block's first table row
    const int r0   = rb + 16 * w;                // wave's 16-row tile
    const int srow = l & 15;
    const int kq   = l >> 4;

    int row = r0 + srow;
    if (row >= K) row = K - 1;                   // clamped rows: LDS-only garbage

    // A-fragments from fp32 values
    bf16x8 af[2];
    #pragma unroll
    for (int kf = 0; kf < 2; ++kf) {
        const float4 x0 = *(const float4*)&values[(size_t)row * 64 + kf * 32 + 8 * kq];
        const float4 x1 = *(const float4*)&values[(size_t)row * 64 + kf * 32 + 8 * kq + 4];
        union { unsigned u[4]; bf16x8 v; } cv;
        cv.u[0] = pack_bf16_rne(x0.x, x0.y);
        cv.u[1] = pack_bf16_rne(x0.z, x0.w);
        cv.u[2] = pack_bf16_rne(x1.x, x1.y);
        cv.u[3] = pack_bf16_rne(x1.z, x1.w);
        af[kf] = cv.v;
    }

    #pragma unroll
    for (int ct = 0; ct < 4; ++ct) {
        const int col = ct * 16 + srow;
        f32x4 acc;
        acc[0] = 0.f; acc[1] = 0.f; acc[2] = 0.f; acc[3] = 0.f;
        #pragma unroll
        for (int kf = 0; kf < 2; ++kf) {
            const int k0 = kf * 32 + 8 * kq;
            union { unsigned u[4]; bf16x8 v; } bv;   // B-frag inline from fp32 W (L1-hot)
            bv.u[0] = pack_bf16_rne(W[(k0 + 0) * 64 + col], W[(k0 + 1) * 64 + col]);
            bv.u[1] = pack_bf16_rne(W[(k0 + 2) * 64 + col], W[(k0 + 3) * 64 + col]);
            bv.u[2] = pack_bf16_rne(W[(k0 + 4) * 64 + col], W[(k0 + 5) * 64 + col]);
            bv.u[3] = pack_bf16_rne(W[(k0 + 6) * 64 + col], W[(k0 + 7) * 64 + col]);
            acc = __builtin_amdgcn_mfma_f32_16x16x32_bf16(af[kf], bv.v, acc, 0, 0, 0);
        }
        #pragma unroll
        for (int r = 0; r < 4; ++r)
            tile[(16 * w + 4 * kq + r) * 64 + col] = bf16_rne1(acc[r]);
    }
    __syncthreads();

    // coalesced writeout: thread t covers 32B of row t>>2
    {
        const int lrow = t >> 2;                 // 0..63
        const int c    = t & 3;                  // 32B chunk
        const int grow = rb + lrow;
        if (grow < K) {
            const uint4* src = (const uint4*)&tile[lrow * 64 + c * 16];
            uint4* dst = (uint4*)(vp + (size_t)grow * 32 + c * 8);
            dst[0] = src[0];
            dst[1] = src[1];
        }
    }
}

// ---- hot kernel: gather + trilinear weighted sum + bias, NO matmul ----
// Wave w owns 16 samples. Lane l: sample srow = l&15, dim octets 8*kq.. and
// 32+8*kq.. (kq = l>>4). 4 lanes per sample cover the 128B valproj row exactly
// once -> line-merged gathers; all 16 issued in one vmcnt window. Output:
// 4 x 16B NT vector stores per lane (wave covers 16 contiguous 256B rows).
__global__ __launch_bounds__(TPB) void gather_interp(
    const unsigned* __restrict__ vp,     // [K,32] u32 = 64 bf16 (128 B/row)
    const float* __restrict__ p,         // [N,3]
    const float* __restrict__ b,         // [64]
    const int*   __restrict__ feats,     // [V,8]
    const int*   __restrict__ vidx,      // [N]
    float* __restrict__ out,             // [N,64]
    int N)
{
    const int t    = threadIdx.x;
    const int l    = t & 63;
    const int w    = t >> 6;
    const int base = blockIdx.x * 64 + 16 * w;
    const int srow = l & 15;
    const int kq   = l >> 4;

    const bool valid = (base + srow) < N;
    int n = base + srow;
    if (!valid) n = N - 1;

    // ---- corner indices + trilinear weights ----
    const int v = vidx[n];
    const int4 f0 = *(const int4*)&feats[(size_t)v * 8];
    const int4 f1 = *(const int4*)&feats[(size_t)v * 8 + 4];

    const float px = p[n * 3 + 0];
    const float py = p[n * 3 + 1];
    const float pz = p[n * 3 + 2];
    const float ox = 1.0f - px, oy = 1.0f - py, oz = 1.0f - pz;
    // corner order: [1,1,1],[1,1,0],[1,0,1],[0,1,1],[1,0,0],[0,1,0],[0,0,1],[0,0,0]
    float wgt[8];
    wgt[0] = px * py * pz;
    wgt[1] = px * py * oz;
    wgt[2] = px * oy * pz;
    wgt[3] = ox * py * pz;
    wgt[4] = px * oy * oz;
    wgt[5] = ox * py * oz;
    wgt[6] = ox * oy * pz;
    wgt[7] = ox * oy * oz;
    const int cidx[8] = {f0.x, f0.y, f0.z, f0.w, f1.x, f1.y, f1.z, f1.w};

    // ---- issue ALL 16 gathers (one vmcnt window, max MLP) ----
    uint4 q0s[8], q1s[8];
    #pragma unroll
    for (int c = 0; c < 8; ++c) {
        const unsigned* row = vp + (size_t)cidx[c] * 32;
        q0s[c] = *(const uint4*)(row + 4 * kq);        // dims 8kq .. 8kq+7
        q1s[c] = *(const uint4*)(row + 16 + 4 * kq);   // dims 32+8kq .. +7
    }

    // ---- weighted accumulate (fp32) ----
    float a0[8] = {0.f,0.f,0.f,0.f,0.f,0.f,0.f,0.f};
    float a1[8] = {0.f,0.f,0.f,0.f,0.f,0.f,0.f,0.f};
    #pragma unroll
    for (int c = 0; c < 8; ++c) {
        const uint4 q0 = q0s[c];
        const uint4 q1 = q1s[c];
        const float wc = wgt[c];
        a0[0] = fmaf(wc, bf_lo(q0.x), a0[0]);
        a0[1] = fmaf(wc, bf_hi(q0.x), a0[1]);
        a0[2] = fmaf(wc, bf_lo(q0.y), a0[2]);
        a0[3] = fmaf(wc, bf_hi(q0.y), a0[3]);
        a0[4] = fmaf(wc, bf_lo(q0.z), a0[4]);
        a0[5] = fmaf(wc, bf_hi(q0.z), a0[5]);
        a0[6] = fmaf(wc, bf_lo(q0.w), a0[6]);
        a0[7] = fmaf(wc, bf_hi(q0.w), a0[7]);
        a1[0] = fmaf(wc, bf_lo(q1.x), a1[0]);
        a1[1] = fmaf(wc, bf_hi(q1.x), a1[1]);
        a1[2] = fmaf(wc, bf_lo(q1.y), a1[2]);
        a1[3] = fmaf(wc, bf_hi(q1.y), a1[3]);
        a1[4] = fmaf(wc, bf_lo(q1.z), a1[4]);
        a1[5] = fmaf(wc, bf_hi(q1.z), a1[5]);
        a1[6] = fmaf(wc, bf_lo(q1.w), a1[6]);
        a1[7] = fmaf(wc, bf_hi(q1.w), a1[7]);
    }

    // ---- bias + store (4 x f32x4 NT vector stores) ----
    if (valid) {
        const float4 b00 = ((const float4*)b)[2 * kq];
        const float4 b01 = ((const float4*)b)[2 * kq + 1];
        const float4 b10 = ((const float4*)b)[8 + 2 * kq];
        const float4 b11 = ((const float4*)b)[8 + 2 * kq + 1];
        f32x4* o4 = (f32x4*)(out + (size_t)n * 64);
        f32x4 v0, v1, v2, v3;
        v0[0] = a0[0] + b00.x; v0[1] = a0[1] + b00.y;
        v0[2] = a0[2] + b00.z; v0[3] = a0[3] + b00.w;
        v1[0] = a0[4] + b01.x; v1[1] = a0[5] + b01.y;
        v1[2] = a0[6] + b01.z; v1[3] = a0[7] + b01.w;
        v2[0] = a1[0] + b10.x; v2[1] = a1[1] + b10.y;
        v2[2] = a1[2] + b10.z; v2[3] = a1[3] + b10.w;
        v3[0] = a1[4] + b11.x; v3[1] = a1[5] + b11.y;
        v3[2] = a1[6] + b11.z; v3[3] = a1[7] + b11.w;
        __builtin_nontemporal_store(v0, o4 + 2 * kq);
        __builtin_nontemporal_store(v1, o4 + 2 * kq + 1);
        __builtin_nontemporal_store(v2, o4 + 8 + 2 * kq);
        __builtin_nontemporal_store(v3, o4 + 8 + 2 * kq + 1);
    }
}

// ---- fallback: proven round-2 fp32 kernel (used only if ws too small) ----
__global__ __launch_bounds__(TPB) void fused_embed_proj_fp32(
    const float* __restrict__ values, const float* __restrict__ p,
    const float* __restrict__ W, const float* __restrict__ b,
    const int* __restrict__ feats, const int* __restrict__ vidx,
    float* __restrict__ out, int N)
{
    __shared__ float featS[64][68];
    __shared__ float Wlds[64][64];

    const int t    = threadIdx.x;
    const int base = blockIdx.x * 64;
    {
        const float4* Wv = (const float4*)W;
        float4*       Wl = (float4*)&Wlds[0][0];
        #pragma unroll
        for (int i = 0; i < 4; ++i) Wl[t + i * TPB] = Wv[t + i * TPB];
    }
    const int g  = t & 15;
    const int sb = t >> 4;

    int   cidx[4][8];
    float wgt[4][8];
    #pragma unroll
    for (int i = 0; i < 4; ++i) {
        const int s = sb + 16 * i;
        int n = base + s;
        if (n >= N) n = N - 1;
        const int v = vidx[n];
        const int4 f0 = *(const int4*)&feats[(size_t)v * 8];
        const int4 f1 = *(const int4*)&feats[(size_t)v * 8 + 4];
        cidx[i][0] = f0.x; cidx[i][1] = f0.y; cidx[i][2] = f0.z; cidx[i][3] = f0.w;
        cidx[i][4] = f1.x; cidx[i][5] = f1.y; cidx[i][6] = f1.z; cidx[i][7] = f1.w;
        const float px = p[n * 3], py = p[n * 3 + 1], pz = p[n * 3 + 2];
        const float ox = 1.f - px, oy = 1.f - py, oz = 1.f - pz;
        wgt[i][0] = px * py * pz; wgt[i][1] = px * py * oz;
        wgt[i][2] = px * oy * pz; wgt[i][3] = ox * py * pz;
        wgt[i][4] = px * oy * oz; wgt[i][5] = ox * py * oz;
        wgt[i][6] = ox * oy * pz; wgt[i][7] = ox * oy * oz;
    }
    #pragma unroll
    for (int i = 0; i < 4; ++i) {
        float4 acc; acc.x = acc.y = acc.z = acc.w = 0.f;
        #pragma unroll
        for (int c = 0; c < 8; ++c) {
            const float4 val = *(const float4*)&values[(size_t)cidx[i][c] * 64 + 4 * g];
            const float w = wgt[i][c];
            acc.x = fmaf(w, val.x, acc.x); acc.y = fmaf(w, val.y, acc.y);
            acc.z = fmaf(w, val.z, acc.z); acc.w = fmaf(w, val.w, acc.w);
        }
        *(float4*)&featS[sb + 16 * i][4 * g] = acc;
    }
    __syncthreads();

    const int tx = t & 15, ty = t >> 4;
    float acc[4][4];
    {
        const float4 bb = ((const float4*)b)[tx];
        #pragma unroll
        for (int j = 0; j < 4; ++j) {
            acc[j][0] = bb.x; acc[j][1] = bb.y; acc[j][2] = bb.z; acc[j][3] = bb.w;
        }
    }
    #pragma unroll 4
    for (int d = 0; d < 64; ++d) {
        const float a0 = featS[4 * ty + 0][d];
        const float a1 = featS[4 * ty + 1][d];
        const float a2 = featS[4 * ty + 2][d];
        const float a3 = featS[4 * ty + 3][d];
        const float4 wr = *(const float4*)&Wlds[d][4 * tx];
        acc[0][0] = fmaf(a0, wr.x, acc[0][0]); acc[0][1] = fmaf(a0, wr.y, acc[0][1]);
        acc[0][2] = fmaf(a0, wr.z, acc[0][2]); acc[0][3] = fmaf(a0, wr.w, acc[0][3]);
        acc[1][0] = fmaf(a1, wr.x, acc[1][0]); acc[1][1] = fmaf(a1, wr.y, acc[1][1]);
        acc[1][2] = fmaf(a1, wr.z, acc[1][2]); acc[1][3] = fmaf(a1, wr.w, acc[1][3]);
        acc[2][0] = fmaf(a2, wr.x, acc[2][0]); acc[2][1] = fmaf(a2, wr.y, acc[2][1]);
        acc[2][2] = fmaf(a2, wr.z, acc[2][2]); acc[2][3] = fmaf(a2, wr.w, acc[2][3]);
        acc[3][0] = fmaf(a3, wr.x, acc[3][0]); acc[3][1] = fmaf(a3, wr.y, acc[3][1]);
        acc[3][2] = fmaf(a3, wr.z, acc[3][2]); acc[3][3] = fmaf(a3, wr.w, acc[3][3]);
    }
    #pragma unroll
    for (int j = 0; j < 4; ++j) {
        const int n = base + 4 * ty + j;
        if (n < N) {
            float4 o; o.x = acc[j][0]; o.y = acc[j][1]; o.z = acc[j][2]; o.w = acc[j][3];
            *(float4*)&out[(size_t)n * 64 + 4 * tx] = o;
        }
    }
}

extern "C" void kernel_launch(void* const* d_in, const int* in_sizes, int n_in,
                              void* d_out, int out_size, void* d_ws, size_t ws_size,
                              hipStream_t stream) {
    const float* values = (const float*)d_in[0];
    const float* p      = (const float*)d_in[1];
    const float* W      = (const float*)d_in[2];
    const float* b      = (const float*)d_in[3];
    const int*   feats  = (const int*)d_in[4];
    const int*   vidx   = (const int*)d_in[5];
    float* out = (float*)d_out;

    const int N  = in_sizes[5];
    const int KD = in_sizes[0];            // K * 64
    const int K  = KD / 64;
    const int nblocks = (N + 63) / 64;

    const size_t need = (size_t)KD * 2;    // valproj bf16 bytes
    if (ws_size >= need) {
        unsigned* vp = (unsigned*)d_ws;
        const int kblocks = (K + 63) / 64;
        proj_table_mfma<<<kblocks, TPB, 0, stream>>>(values, W, vp, K);
        gather_interp<<<nblocks, TPB, 0, stream>>>(
            vp, p, b, feats, vidx, out, N);
    } else {
        fused_embed_proj_fp32<<<nblocks, TPB, 0, stream>>>(
            values, p, W, b, feats, vidx, out, N);
    }
}